// Round 3
// baseline (138.287 us; speedup 1.0000x reference)
//
#include <hip/hip_runtime.h>

// Problem constants (from reference setup_inputs)
constexpr int Bx = 8;
constexpr int Nn = 16384;   // power of two -> shift/mask index math
constexpr int Vv = 12;
constexpr long long TOT = (long long)Bx * Nn * Vv;   // 1,572,864 output elems
constexpr int NB = (Bx * Nn) / 256;                  // 512 blocks, 2 per CU
constexpr unsigned long long MAGIC = 0x5ca1ab1ef00df00dULL;

__device__ __forceinline__ float lk(float x) { return fmaxf(x, 0.2f * x); }

// Single fused kernel. Phase 1: each thread computes its 12 pre-BN y values
// (kept in registers) and the block reduces (sum, sumsq) into a packed 64-bit
// partial + magic flag in ws (agent-scope atomics — flags need no init since
// ws poison != MAGIC). Phase 2: spin-acquire all 512 flags, redundantly
// reduce the 4 KB partial array per block, normalize registers, store once.
// __launch_bounds__(256,2): 4 waves/block, >=2 waves/EU -> 2 blocks/CU,
// all 512 blocks co-resident (spin barrier is safe).
__global__ __launch_bounds__(256, 2) void nlmp_fused(
    const float* __restrict__ F,
    const float* __restrict__ W1, const float* __restrict__ b1,
    const float* __restrict__ W2, const float* __restrict__ b2,
    const float* __restrict__ W3, const float* __restrict__ b3,
    const float* __restrict__ cw, const float* __restrict__ cb,
    const float* __restrict__ gamma, const float* __restrict__ beta,
    float* __restrict__ out,
    unsigned long long* __restrict__ part,   // 512 packed (sum, sumsq)
    unsigned long long* __restrict__ flag)   // 512 magic flags
{
    const int tid = threadIdx.x;
    const int t = blockIdx.x * 256 + tid;    // in [0, B*N)

    // tiny weight set: broadcast loads, L1/L2 cached
    const float w100 = W1[0], w101 = W1[1], w110 = W1[2], w111 = W1[3];
    const float bb10 = b1[0], bb11 = b1[1];
    const float w200 = W2[0], w201 = W2[1], w210 = W2[2], w211 = W2[3];
    const float bb20 = b2[0], bb21 = b2[1];
    const float w30 = W3[0], w31 = W3[1], bb3 = b3[0];
    const float c0 = cw[0], c1 = cw[1], cbv = cb[0];

    // F[b,n,0..11]: contiguous 48 B -> three float4 loads
    float f[Vv];
    const float4* fp = reinterpret_cast<const float4*>(F + (long long)t * Vv);
    float4 q0 = fp[0], q1 = fp[1], q2 = fp[2];
    f[0] = q0.x; f[1] = q0.y; f[2]  = q0.z; f[3]  = q0.w;
    f[4] = q1.x; f[5] = q1.y; f[6]  = q1.z; f[7]  = q1.w;
    f[8] = q2.x; f[9] = q2.y; f[10] = q2.z; f[11] = q2.w;

    // Layer-1 factored: h[c](i,j) = lk( W1[c,0]*F[j] + (W1[c,1]*F[i] + b1[c]) )
    float a0[Vv], a1[Vv], p0[Vv], p1[Vv];
#pragma unroll
    for (int v = 0; v < Vv; ++v) {
        a0[v] = w100 * f[v];
        a1[v] = w110 * f[v];
        p0[v] = fmaf(w101, f[v], bb10);
        p1[v] = fmaf(w111, f[v], bb11);
    }

    float yv[Vv];
    float s = 0.f, ss = 0.f;
#pragma unroll
    for (int i = 0; i < Vv; ++i) {
        float ms = 0.f;
#pragma unroll
        for (int j = 0; j < Vv; ++j) {
            float h0 = lk(a0[j] + p0[i]);
            float h1 = lk(a1[j] + p1[i]);
            float g0 = lk(fmaf(w200, h0, fmaf(w201, h1, bb20)));
            float g1 = lk(fmaf(w210, h0, fmaf(w211, h1, bb21)));
            ms += lk(fmaf(w30, g0, fmaf(w31, g1, bb3)));
        }
        float v = fmaf(c0, f[i], fmaf(c1, ms, cbv));
        yv[i] = v;
        s += v;
        ss = fmaf(v, v, ss);
    }

    // block reduction: wave(64) shuffles, then LDS across the 4 waves
#pragma unroll
    for (int off = 32; off > 0; off >>= 1) {
        s  += __shfl_down(s,  off, 64);
        ss += __shfl_down(ss, off, 64);
    }
    __shared__ float ls[4], lss[4];
    __shared__ float coef[3];   // scale, mean, shift
    const int lane = tid & 63;
    const int wave = tid >> 6;
    if (lane == 0) { ls[wave] = s; lss[wave] = ss; }
    __syncthreads();
    if (tid == 0) {
        float2 p;
        p.x = ls[0]  + ls[1]  + ls[2]  + ls[3];
        p.y = lss[0] + lss[1] + lss[2] + lss[3];
        unsigned long long packed;
        __builtin_memcpy(&packed, &p, 8);
        __hip_atomic_store(&part[blockIdx.x], packed,
                           __ATOMIC_RELAXED, __HIP_MEMORY_SCOPE_AGENT);
        __hip_atomic_store(&flag[blockIdx.x], MAGIC,
                           __ATOMIC_RELEASE, __HIP_MEMORY_SCOPE_AGENT);
    }

    // grid barrier: thread tid polls flags tid and tid+256 (all 512 covered)
    while (__hip_atomic_load(&flag[tid], __ATOMIC_ACQUIRE,
                             __HIP_MEMORY_SCOPE_AGENT) != MAGIC)
        __builtin_amdgcn_s_sleep(1);
    while (__hip_atomic_load(&flag[tid + 256], __ATOMIC_ACQUIRE,
                             __HIP_MEMORY_SCOPE_AGENT) != MAGIC)
        __builtin_amdgcn_s_sleep(1);

    // redundant per-block reduction of the 512 partials (4 KB)
    unsigned long long pa = __hip_atomic_load(&part[tid], __ATOMIC_RELAXED,
                                              __HIP_MEMORY_SCOPE_AGENT);
    unsigned long long pb = __hip_atomic_load(&part[tid + 256], __ATOMIC_RELAXED,
                                              __HIP_MEMORY_SCOPE_AGENT);
    float2 fa, fb;
    __builtin_memcpy(&fa, &pa, 8);
    __builtin_memcpy(&fb, &pb, 8);
    float rs  = fa.x + fb.x;
    float rss = fa.y + fb.y;
#pragma unroll
    for (int off = 32; off > 0; off >>= 1) {
        rs  += __shfl_down(rs,  off, 64);
        rss += __shfl_down(rss, off, 64);
    }
    __syncthreads();   // ls/lss reuse
    if (lane == 0) { ls[wave] = rs; lss[wave] = rss; }
    __syncthreads();
    if (tid == 0) {
        double S  = (double)ls[0]  + ls[1]  + ls[2]  + ls[3];
        double SS = (double)lss[0] + lss[1] + lss[2] + lss[3];
        double mean = S / (double)TOT;
        double var  = SS / (double)TOT - mean * mean;
        coef[0] = (float)(1.0 / sqrt(var + 1e-5)) * gamma[0];
        coef[1] = (float)mean;
        coef[2] = beta[0];
    }
    __syncthreads();
    const float scale = coef[0], mb = coef[1], bt = coef[2];

    // normalize registers, single coalesced write pass
    const int b = t >> 14;        // / 16384
    const int n = t & (Nn - 1);
#pragma unroll
    for (int i = 0; i < Vv; ++i) {
        out[((long long)b * Vv + i) * Nn + n] = lk(fmaf(yv[i] - mb, scale, bt));
    }
}

extern "C" void kernel_launch(void* const* d_in, const int* in_sizes, int n_in,
                              void* d_out, int out_size, void* d_ws, size_t ws_size,
                              hipStream_t stream) {
    const float* F  = (const float*)d_in[0];
    const float* W1 = (const float*)d_in[1];
    const float* b1 = (const float*)d_in[2];
    const float* W2 = (const float*)d_in[3];
    const float* b2 = (const float*)d_in[4];
    const float* W3 = (const float*)d_in[5];
    const float* b3 = (const float*)d_in[6];
    const float* cw = (const float*)d_in[7];
    const float* cb = (const float*)d_in[8];
    const float* gamma = (const float*)d_in[9];
    const float* beta  = (const float*)d_in[10];

    float* out = (float*)d_out;
    unsigned long long* part = (unsigned long long*)d_ws;            // 512 × 8 B
    unsigned long long* flag = (unsigned long long*)((char*)d_ws + 4096); // 512 × 8 B

    nlmp_fused<<<NB, 256, 0, stream>>>(
        F, W1, b1, W2, b2, W3, b3, cw, cb, gamma, beta, out, part, flag);
}

// Round 4
// 137.994 us; speedup vs baseline: 1.0021x; 1.0021x over previous
//
#include <hip/hip_runtime.h>

// Problem constants (from reference setup_inputs)
constexpr int Bx = 8;
constexpr int Nn = 16384;   // power of two -> shift/mask index math
constexpr int Vv = 12;
constexpr long long TOT = (long long)Bx * Nn * Vv;   // 1,572,864 output elems
constexpr int NB = (Bx * Nn) / 256;                  // 512 blocks, 2 per CU
constexpr unsigned long long MAGIC = 0x5ca1ab1ef00df00dULL;

__device__ __forceinline__ float lk(float x) { return fmaxf(x, 0.2f * x); }

// Single fused kernel, lightweight grid barrier.
// Phase 1: each thread computes its 12 pre-BN y values (kept in registers);
// block reduces (sum,sumsq) -> packed 64-bit partial + MAGIC flag in ws
// (agent-scope; init-free since ws poison != MAGIC).
// Barrier: ONLY wave 0 of each block polls the 512 flags (lane L checks
// L, L+64, ..., L+448) with s_sleep(32) backoff; waves 1-3 park at
// __syncthreads() with zero memory traffic. This avoids the round-3
// pathology where 2048 spinning waves starved the still-computing blocks.
// Phase 2: redundant per-block reduction of the 4 KB partial array,
// normalize registers, single coalesced store pass.
// __launch_bounds__(256,2): 2 blocks/CU -> all 512 blocks co-resident
// (empirically confirmed in round 3: no deadlock).
__global__ __launch_bounds__(256, 2) void nlmp_fused(
    const float* __restrict__ F,
    const float* __restrict__ W1, const float* __restrict__ b1,
    const float* __restrict__ W2, const float* __restrict__ b2,
    const float* __restrict__ W3, const float* __restrict__ b3,
    const float* __restrict__ cw, const float* __restrict__ cb,
    const float* __restrict__ gamma, const float* __restrict__ beta,
    float* __restrict__ out,
    unsigned long long* __restrict__ part,   // 512 packed (sum, sumsq)
    unsigned long long* __restrict__ flag)   // 512 magic flags
{
    const int tid = threadIdx.x;
    const int t = blockIdx.x * 256 + tid;    // in [0, B*N)
    const int lane = tid & 63;
    const int wave = tid >> 6;

    // tiny weight set: broadcast loads, L1/L2 cached
    const float w100 = W1[0], w101 = W1[1], w110 = W1[2], w111 = W1[3];
    const float bb10 = b1[0], bb11 = b1[1];
    const float w200 = W2[0], w201 = W2[1], w210 = W2[2], w211 = W2[3];
    const float bb20 = b2[0], bb21 = b2[1];
    const float w30 = W3[0], w31 = W3[1], bb3 = b3[0];
    const float c0 = cw[0], c1 = cw[1], cbv = cb[0];

    // F[b,n,0..11]: contiguous 48 B -> three float4 loads
    float f[Vv];
    const float4* fp = reinterpret_cast<const float4*>(F + (long long)t * Vv);
    float4 q0 = fp[0], q1 = fp[1], q2 = fp[2];
    f[0] = q0.x; f[1] = q0.y; f[2]  = q0.z; f[3]  = q0.w;
    f[4] = q1.x; f[5] = q1.y; f[6]  = q1.z; f[7]  = q1.w;
    f[8] = q2.x; f[9] = q2.y; f[10] = q2.z; f[11] = q2.w;

    // Layer-1 factored: h[c](i,j) = lk( W1[c,0]*F[j] + (W1[c,1]*F[i] + b1[c]) )
    float a0[Vv], a1[Vv], p0[Vv], p1[Vv];
#pragma unroll
    for (int v = 0; v < Vv; ++v) {
        a0[v] = w100 * f[v];
        a1[v] = w110 * f[v];
        p0[v] = fmaf(w101, f[v], bb10);
        p1[v] = fmaf(w111, f[v], bb11);
    }

    float yv[Vv];
    float s = 0.f, ss = 0.f;
#pragma unroll
    for (int i = 0; i < Vv; ++i) {
        float ms = 0.f;
#pragma unroll
        for (int j = 0; j < Vv; ++j) {
            float h0 = lk(a0[j] + p0[i]);
            float h1 = lk(a1[j] + p1[i]);
            float g0 = lk(fmaf(w200, h0, fmaf(w201, h1, bb20)));
            float g1 = lk(fmaf(w210, h0, fmaf(w211, h1, bb21)));
            ms += lk(fmaf(w30, g0, fmaf(w31, g1, bb3)));
        }
        float v = fmaf(c0, f[i], fmaf(c1, ms, cbv));
        yv[i] = v;
        s += v;
        ss = fmaf(v, v, ss);
    }

    // block reduction: wave(64) shuffles, then LDS across the 4 waves
#pragma unroll
    for (int off = 32; off > 0; off >>= 1) {
        s  += __shfl_down(s,  off, 64);
        ss += __shfl_down(ss, off, 64);
    }
    __shared__ float ls[4], lss[4];
    __shared__ float coef[3];   // scale, mean, shift
    if (lane == 0) { ls[wave] = s; lss[wave] = ss; }
    __syncthreads();
    if (tid == 0) {
        float2 p;
        p.x = ls[0]  + ls[1]  + ls[2]  + ls[3];
        p.y = lss[0] + lss[1] + lss[2] + lss[3];
        unsigned long long packed;
        __builtin_memcpy(&packed, &p, 8);
        __hip_atomic_store(&part[blockIdx.x], packed,
                           __ATOMIC_RELAXED, __HIP_MEMORY_SCOPE_AGENT);
        __hip_atomic_store(&flag[blockIdx.x], MAGIC,
                           __ATOMIC_RELEASE, __HIP_MEMORY_SCOPE_AGENT);
    }

    // lightweight grid barrier: wave 0 only, big backoff; others park at
    // the __syncthreads below (no polling traffic from them).
    if (wave == 0) {
        for (;;) {
            bool mine = true;
#pragma unroll
            for (int k = 0; k < 8; ++k) {
                unsigned long long v = __hip_atomic_load(
                    &flag[lane + 64 * k], __ATOMIC_ACQUIRE,
                    __HIP_MEMORY_SCOPE_AGENT);
                mine &= (v == MAGIC);
            }
            if (__all(mine)) break;
            __builtin_amdgcn_s_sleep(32);   // ~2k cycles backoff
        }
    }
    __syncthreads();

    // redundant per-block reduction of the 512 partials (4 KB, coherent reads)
    unsigned long long pa = __hip_atomic_load(&part[tid], __ATOMIC_RELAXED,
                                              __HIP_MEMORY_SCOPE_AGENT);
    unsigned long long pb = __hip_atomic_load(&part[tid + 256], __ATOMIC_RELAXED,
                                              __HIP_MEMORY_SCOPE_AGENT);
    float2 fa, fb;
    __builtin_memcpy(&fa, &pa, 8);
    __builtin_memcpy(&fb, &pb, 8);
    float rs  = fa.x + fb.x;
    float rss = fa.y + fb.y;
#pragma unroll
    for (int off = 32; off > 0; off >>= 1) {
        rs  += __shfl_down(rs,  off, 64);
        rss += __shfl_down(rss, off, 64);
    }
    if (lane == 0) { ls[wave] = rs; lss[wave] = rss; }
    __syncthreads();
    if (tid == 0) {
        double S  = (double)ls[0]  + ls[1]  + ls[2]  + ls[3];
        double SS = (double)lss[0] + lss[1] + lss[2] + lss[3];
        double mean = S / (double)TOT;
        double var  = SS / (double)TOT - mean * mean;
        coef[0] = (float)(1.0 / sqrt(var + 1e-5)) * gamma[0];
        coef[1] = (float)mean;
        coef[2] = beta[0];
    }
    __syncthreads();
    const float scale = coef[0], mb = coef[1], bt = coef[2];

    // normalize registers, single coalesced write pass
    const int b = t >> 14;        // / 16384
    const int n = t & (Nn - 1);
#pragma unroll
    for (int i = 0; i < Vv; ++i) {
        out[((long long)b * Vv + i) * Nn + n] = lk(fmaf(yv[i] - mb, scale, bt));
    }
}

extern "C" void kernel_launch(void* const* d_in, const int* in_sizes, int n_in,
                              void* d_out, int out_size, void* d_ws, size_t ws_size,
                              hipStream_t stream) {
    const float* F  = (const float*)d_in[0];
    const float* W1 = (const float*)d_in[1];
    const float* b1 = (const float*)d_in[2];
    const float* W2 = (const float*)d_in[3];
    const float* b2 = (const float*)d_in[4];
    const float* W3 = (const float*)d_in[5];
    const float* b3 = (const float*)d_in[6];
    const float* cw = (const float*)d_in[7];
    const float* cb = (const float*)d_in[8];
    const float* gamma = (const float*)d_in[9];
    const float* beta  = (const float*)d_in[10];

    float* out = (float*)d_out;
    unsigned long long* part = (unsigned long long*)d_ws;                 // 512 × 8 B
    unsigned long long* flag = (unsigned long long*)((char*)d_ws + 4096); // 512 × 8 B

    nlmp_fused<<<NB, 256, 0, stream>>>(
        F, W1, b1, W2, b2, W3, b3, cw, cb, gamma, beta, out, part, flag);
}

// Round 5
// 91.615 us; speedup vs baseline: 1.5094x; 1.5062x over previous
//
#include <hip/hip_runtime.h>

// Problem constants (from reference setup_inputs)
constexpr int Bx = 8;
constexpr int Nn = 16384;   // power of two -> shift/mask index math
constexpr int Vv = 12;
constexpr long long TOT = (long long)Bx * Nn * Vv;   // 1,572,864 output elems
constexpr int NB1 = (Bx * Nn) / 256;                 // 512 compute blocks

typedef float v2f __attribute__((ext_vector_type(2)));

__device__ __forceinline__ float lk(float x) { return fmaxf(x, 0.2f * x); }
__device__ __forceinline__ v2f lkv(v2f x) {
    return __builtin_elementwise_max(x, x * 0.2f);   // -> v_pk_max_f32
}

// NOTE (rounds 3-4): single-kernel fusion with a grid-wide spin barrier
// measured 60-90us of flat stall regardless of polling intensity (72us with
// 2048 polling waves, 100us with 512-wave/32x-backoff polling). Kernel-boundary
// coherence is cheaper than any software barrier here. Two kernels it is.

// Kernel 1: one thread per (b,n). Computes pre-BN y[b,v,n] into `y`
// (layout [B,V,N] == final output layout) and writes one float2 partial
// (sum, sumsq) per block into ws — plain store, no atomics, no init needed.
// Inner pair-loop processes j in pairs as <2 x float> so the backend emits
// packed fp32 (v_pk_fma/add/mul/max_f32), halving VALU issue on the
// 144-iteration hot loop.
__global__ __launch_bounds__(256) void nlmp_compute(
    const float* __restrict__ F,
    const float* __restrict__ W1, const float* __restrict__ b1,
    const float* __restrict__ W2, const float* __restrict__ b2,
    const float* __restrict__ W3, const float* __restrict__ b3,
    const float* __restrict__ cw, const float* __restrict__ cb,
    float* __restrict__ y, float2* __restrict__ part)
{
    const int t = blockIdx.x * blockDim.x + threadIdx.x;  // in [0, B*N)

    // tiny weight set: broadcast loads, L1/L2 cached
    const float w100 = W1[0], w101 = W1[1], w110 = W1[2], w111 = W1[3];
    const float bb10 = b1[0], bb11 = b1[1];
    const float w200 = W2[0], w201 = W2[1], w210 = W2[2], w211 = W2[3];
    const float bb20 = b2[0], bb21 = b2[1];
    const float w30 = W3[0], w31 = W3[1], bb3 = b3[0];
    const float c0 = cw[0], c1 = cw[1], cbv = cb[0];

    // F[b,n,0..11]: contiguous 48 B -> three float4 loads
    float f[Vv];
    const float4* fp = reinterpret_cast<const float4*>(F + (long long)t * Vv);
    float4 q0 = fp[0], q1 = fp[1], q2 = fp[2];
    f[0] = q0.x; f[1] = q0.y; f[2]  = q0.z; f[3]  = q0.w;
    f[4] = q1.x; f[5] = q1.y; f[6]  = q1.z; f[7]  = q1.w;
    f[8] = q2.x; f[9] = q2.y; f[10] = q2.z; f[11] = q2.w;

    // Layer-1 factored: h[c](i,j) = lk( W1[c,0]*F[j] + (W1[c,1]*F[i] + b1[c]) )
    // j-dependent partials packed in pairs for v_pk ops
    v2f a0v[Vv / 2], a1v[Vv / 2];
    float p0[Vv], p1[Vv];
#pragma unroll
    for (int v = 0; v < Vv / 2; ++v) {
        v2f fv = {f[2 * v], f[2 * v + 1]};
        a0v[v] = fv * w100;
        a1v[v] = fv * w110;
    }
#pragma unroll
    for (int v = 0; v < Vv; ++v) {
        p0[v] = fmaf(w101, f[v], bb10);
        p1[v] = fmaf(w111, f[v], bb11);
    }

    const int b = t >> 14;        // / 16384
    const int n = t & (Nn - 1);

    float s = 0.f, ss = 0.f;
#pragma unroll
    for (int i = 0; i < Vv; ++i) {
        v2f p0i = {p0[i], p0[i]};
        v2f p1i = {p1[i], p1[i]};
        v2f msv = {0.f, 0.f};
#pragma unroll
        for (int jj = 0; jj < Vv / 2; ++jj) {
            v2f h0 = lkv(a0v[jj] + p0i);
            v2f h1 = lkv(a1v[jj] + p1i);
            v2f g0 = lkv(h0 * w200 + h1 * w201 + bb20);  // contracts to pk_fma
            v2f g1 = lkv(h0 * w210 + h1 * w211 + bb21);
            msv += lkv(g0 * w30 + g1 * w31 + bb3);
        }
        float ms = msv.x + msv.y;
        float yv = fmaf(c0, f[i], fmaf(c1, ms, cbv));
        y[((long long)b * Vv + i) * Nn + n] = yv;   // coalesced per i across n
        s += yv;
        ss = fmaf(yv, yv, ss);
    }

    // wave(64) shuffle reduction, then block reduction, one plain store/block
#pragma unroll
    for (int off = 32; off > 0; off >>= 1) {
        s  += __shfl_down(s,  off, 64);
        ss += __shfl_down(ss, off, 64);
    }
    __shared__ float ls[4], lss[4];
    const int lane = threadIdx.x & 63;
    const int wave = threadIdx.x >> 6;
    if (lane == 0) { ls[wave] = s; lss[wave] = ss; }
    __syncthreads();
    if (threadIdx.x == 0) {
        float2 p;
        p.x = ls[0]  + ls[1]  + ls[2]  + ls[3];
        p.y = lss[0] + lss[1] + lss[2] + lss[3];
        part[blockIdx.x] = p;
    }
}

// Kernel 2: every block redundantly reduces the 512 block-partials (4 KB,
// L2-resident; kernel boundary guarantees coherence), then applies BN
// (training-mode batch stats) + leaky in place, float4-vectorized.
__global__ __launch_bounds__(256) void nlmp_finalize(
    float* __restrict__ y, const float2* __restrict__ part,
    const float* __restrict__ gamma, const float* __restrict__ beta)
{
    const int t = threadIdx.x;

    // reduce 512 partials: thread t handles part[t] and part[t+256]
    float2 pa = part[t], pb = part[t + 256];
    float s  = pa.x + pb.x;
    float ss = pa.y + pb.y;
#pragma unroll
    for (int off = 32; off > 0; off >>= 1) {
        s  += __shfl_down(s,  off, 64);
        ss += __shfl_down(ss, off, 64);
    }
    __shared__ float ls[4], lss[4];
    __shared__ float coef[3];   // scale, mean, shift
    const int lane = t & 63;
    const int wave = t >> 6;
    if (lane == 0) { ls[wave] = s; lss[wave] = ss; }
    __syncthreads();
    if (t == 0) {
        double S  = (double)ls[0]  + ls[1]  + ls[2]  + ls[3];
        double SS = (double)lss[0] + lss[1] + lss[2] + lss[3];
        double mean = S / (double)TOT;
        double var  = SS / (double)TOT - mean * mean;
        coef[0] = (float)(1.0 / sqrt(var + 1e-5)) * gamma[0];
        coef[1] = (float)mean;
        coef[2] = beta[0];
    }
    __syncthreads();
    const float scale = coef[0], mb = coef[1], bt = coef[2];

    const long long idx4 = (long long)blockIdx.x * blockDim.x + t;
    float4 v = reinterpret_cast<float4*>(y)[idx4];
    float4 o;
    o.x = lk(fmaf(v.x - mb, scale, bt));
    o.y = lk(fmaf(v.y - mb, scale, bt));
    o.z = lk(fmaf(v.z - mb, scale, bt));
    o.w = lk(fmaf(v.w - mb, scale, bt));
    reinterpret_cast<float4*>(y)[idx4] = o;
}

extern "C" void kernel_launch(void* const* d_in, const int* in_sizes, int n_in,
                              void* d_out, int out_size, void* d_ws, size_t ws_size,
                              hipStream_t stream) {
    const float* F  = (const float*)d_in[0];
    const float* W1 = (const float*)d_in[1];
    const float* b1 = (const float*)d_in[2];
    const float* W2 = (const float*)d_in[3];
    const float* b2 = (const float*)d_in[4];
    const float* W3 = (const float*)d_in[5];
    const float* b3 = (const float*)d_in[6];
    const float* cw = (const float*)d_in[7];
    const float* cb = (const float*)d_in[8];
    const float* gamma = (const float*)d_in[9];
    const float* beta  = (const float*)d_in[10];

    float*  out  = (float*)d_out;      // pre-BN scratch, finalized in place
    float2* part = (float2*)d_ws;      // 512 block partials (sum, sumsq)

    nlmp_compute<<<NB1, 256, 0, stream>>>(
        F, W1, b1, W2, b2, W3, b3, cw, cb, out, part);

    nlmp_finalize<<<(int)(TOT / 4 / 256), 256, 0, stream>>>(out, part, gamma, beta);
}

// Round 6
// 90.288 us; speedup vs baseline: 1.5316x; 1.0147x over previous
//
#include <hip/hip_runtime.h>

// Problem constants (from reference setup_inputs)
constexpr int Bx = 8;
constexpr int Nn = 16384;   // power of two -> shift/mask index math
constexpr int Vv = 12;
constexpr long long TOT = (long long)Bx * Nn * Vv;   // 1,572,864 output elems
constexpr int NB1 = (Bx * Nn) / 256;                 // 512 compute blocks

__device__ __forceinline__ float lk(float x) { return fmaxf(x, 0.2f * x); }

// Experiment log (measured end-to-end, harness fills ~75us are fixed):
//  R1: 3 dispatches (memset+compute+finalize, atomics)          -> 100.7us
//  R2: 2 dispatches (plain partial stores, no atomics)          ->  89.9us  BEST
//  R3: 1 dispatch, grid spin barrier (2048 polling waves)       -> 138.3us
//  R4: 1 dispatch, wave0-only polling + 32x backoff             -> 138.0us
//      (barrier stall is flat ~60-90us regardless of poll rate — kernel
//       boundary coherence is cheaper than any software grid barrier here)
//  R5: R2 + packed <2xfloat> inner loop                         ->  91.6us
//      (pk-fp32 regressed: pack/unpack + horizontal add overhead)
// This file: R2 scalar structure + finalize y-load hoisted above the
// partial reduction (VMEM latency overlaps the shuffle reduction).

// Kernel 1: one thread per (b,n). Computes pre-BN y[b,v,n] into `y`
// (layout [B,V,N] == final output layout) and writes one float2 partial
// (sum, sumsq) per block into ws — plain store, no atomics, no init needed.
__global__ __launch_bounds__(256) void nlmp_compute(
    const float* __restrict__ F,
    const float* __restrict__ W1, const float* __restrict__ b1,
    const float* __restrict__ W2, const float* __restrict__ b2,
    const float* __restrict__ W3, const float* __restrict__ b3,
    const float* __restrict__ cw, const float* __restrict__ cb,
    float* __restrict__ y, float2* __restrict__ part)
{
    const int t = blockIdx.x * blockDim.x + threadIdx.x;  // in [0, B*N)

    // tiny weight set: broadcast loads, L1/L2 cached
    const float w100 = W1[0], w101 = W1[1], w110 = W1[2], w111 = W1[3];
    const float bb10 = b1[0], bb11 = b1[1];
    const float w200 = W2[0], w201 = W2[1], w210 = W2[2], w211 = W2[3];
    const float bb20 = b2[0], bb21 = b2[1];
    const float w30 = W3[0], w31 = W3[1], bb3 = b3[0];
    const float c0 = cw[0], c1 = cw[1], cbv = cb[0];

    // F[b,n,0..11]: contiguous 48 B -> three float4 loads
    float f[Vv];
    const float4* fp = reinterpret_cast<const float4*>(F + (long long)t * Vv);
    float4 q0 = fp[0], q1 = fp[1], q2 = fp[2];
    f[0] = q0.x; f[1] = q0.y; f[2]  = q0.z; f[3]  = q0.w;
    f[4] = q1.x; f[5] = q1.y; f[6]  = q1.z; f[7]  = q1.w;
    f[8] = q2.x; f[9] = q2.y; f[10] = q2.z; f[11] = q2.w;

    // Layer-1 factored: h[c](i,j) = lk( W1[c,0]*F[j] + (W1[c,1]*F[i] + b1[c]) )
    float a0[Vv], a1[Vv], p0[Vv], p1[Vv];
#pragma unroll
    for (int v = 0; v < Vv; ++v) {
        a0[v] = w100 * f[v];
        a1[v] = w110 * f[v];
        p0[v] = fmaf(w101, f[v], bb10);
        p1[v] = fmaf(w111, f[v], bb11);
    }

    const int b = t >> 14;        // / 16384
    const int n = t & (Nn - 1);

    float s = 0.f, ss = 0.f;
#pragma unroll
    for (int i = 0; i < Vv; ++i) {
        float ms = 0.f;
#pragma unroll
        for (int j = 0; j < Vv; ++j) {
            float h0 = lk(a0[j] + p0[i]);
            float h1 = lk(a1[j] + p1[i]);
            float g0 = lk(fmaf(w200, h0, fmaf(w201, h1, bb20)));
            float g1 = lk(fmaf(w210, h0, fmaf(w211, h1, bb21)));
            ms += lk(fmaf(w30, g0, fmaf(w31, g1, bb3)));
        }
        float yv = fmaf(c0, f[i], fmaf(c1, ms, cbv));
        y[((long long)b * Vv + i) * Nn + n] = yv;   // coalesced per i across n
        s += yv;
        ss = fmaf(yv, yv, ss);
    }

    // wave(64) shuffle reduction, then block reduction, one plain store/block
#pragma unroll
    for (int off = 32; off > 0; off >>= 1) {
        s  += __shfl_down(s,  off, 64);
        ss += __shfl_down(ss, off, 64);
    }
    __shared__ float ls[4], lss[4];
    const int lane = threadIdx.x & 63;
    const int wave = threadIdx.x >> 6;
    if (lane == 0) { ls[wave] = s; lss[wave] = ss; }
    __syncthreads();
    if (threadIdx.x == 0) {
        float2 p;
        p.x = ls[0]  + ls[1]  + ls[2]  + ls[3];
        p.y = lss[0] + lss[1] + lss[2] + lss[3];
        part[blockIdx.x] = p;
    }
}

// Kernel 2: every block redundantly reduces the 512 block-partials (4 KB,
// L2/L3-resident; kernel boundary guarantees coherence), then applies BN
// (training-mode batch stats) + leaky in place, float4-vectorized.
// The y-load is issued FIRST so its VMEM latency overlaps the reduction.
__global__ __launch_bounds__(256) void nlmp_finalize(
    float* __restrict__ y, const float2* __restrict__ part,
    const float* __restrict__ gamma, const float* __restrict__ beta)
{
    const int t = threadIdx.x;

    // issue the main data load up front (independent of the reduction)
    const long long idx4 = (long long)blockIdx.x * blockDim.x + t;
    float4 v = reinterpret_cast<float4*>(y)[idx4];

    // reduce 512 partials: thread t handles part[t] and part[t+256]
    float2 pa = part[t], pb = part[t + 256];
    float s  = pa.x + pb.x;
    float ss = pa.y + pb.y;
#pragma unroll
    for (int off = 32; off > 0; off >>= 1) {
        s  += __shfl_down(s,  off, 64);
        ss += __shfl_down(ss, off, 64);
    }
    __shared__ float ls[4], lss[4];
    __shared__ float coef[3];   // scale, mean, shift
    const int lane = t & 63;
    const int wave = t >> 6;
    if (lane == 0) { ls[wave] = s; lss[wave] = ss; }
    __syncthreads();
    if (t == 0) {
        double S  = (double)ls[0]  + ls[1]  + ls[2]  + ls[3];
        double SS = (double)lss[0] + lss[1] + lss[2] + lss[3];
        double mean = S / (double)TOT;
        double var  = SS / (double)TOT - mean * mean;
        coef[0] = (float)(1.0 / sqrt(var + 1e-5)) * gamma[0];
        coef[1] = (float)mean;
        coef[2] = beta[0];
    }
    __syncthreads();
    const float scale = coef[0], mb = coef[1], bt = coef[2];

    float4 o;
    o.x = lk(fmaf(v.x - mb, scale, bt));
    o.y = lk(fmaf(v.y - mb, scale, bt));
    o.z = lk(fmaf(v.z - mb, scale, bt));
    o.w = lk(fmaf(v.w - mb, scale, bt));
    reinterpret_cast<float4*>(y)[idx4] = o;
}

extern "C" void kernel_launch(void* const* d_in, const int* in_sizes, int n_in,
                              void* d_out, int out_size, void* d_ws, size_t ws_size,
                              hipStream_t stream) {
    const float* F  = (const float*)d_in[0];
    const float* W1 = (const float*)d_in[1];
    const float* b1 = (const float*)d_in[2];
    const float* W2 = (const float*)d_in[3];
    const float* b2 = (const float*)d_in[4];
    const float* W3 = (const float*)d_in[5];
    const float* b3 = (const float*)d_in[6];
    const float* cw = (const float*)d_in[7];
    const float* cb = (const float*)d_in[8];
    const float* gamma = (const float*)d_in[9];
    const float* beta  = (const float*)d_in[10];

    float*  out  = (float*)d_out;      // pre-BN scratch, finalized in place
    float2* part = (float2*)d_ws;      // 512 block partials (sum, sumsq)

    nlmp_compute<<<NB1, 256, 0, stream>>>(
        F, W1, b1, W2, b2, W3, b3, cw, cb, out, part);

    nlmp_finalize<<<(int)(TOT / 4 / 256), 256, 0, stream>>>(out, part, gamma, beta);
}